// Round 4
// baseline (523.581 us; speedup 1.0000x reference)
//
#include <hip/hip_runtime.h>
#include <hip/hip_bf16.h>

// GATPooling fused kernel for MI355X (gfx950).
//
// pooled[b] = (sum_i x_i * e_i) / (sum_i e_i), e_i = exp(score_i); scores are O(1)
// so no segment-max pass is needed -> single pass over x (819 MB) -> ~131 us roofline.
//
// R4: persistent 8-wave blocks with register prefetch (next tile-pair's loads in
// flight under current pair's compute), dual-tile MFMA iterations (one W1 B-frag
// read feeds 2 MFMAs), and a barrier-free per-wave pooling path (butterfly over
// the 16 lr-lanes + direct atomics). R3's 262 us was a ~50% HBM duty cycle from
// the unpipelined load->sync->compute structure.
//
// ws layout: num[nseg*128] f32 | denom[nseg] f32 | w1bf[128*128] bf16 (pre-swizzled)

#define H 128
#define TILE 128
#define NB 512

typedef __attribute__((ext_vector_type(8))) __bf16 bf16x8;
typedef __attribute__((ext_vector_type(4))) float f32x4;

__global__ void gat_init(const float* __restrict__ W1, float* __restrict__ num,
                         float* __restrict__ denom, unsigned short* __restrict__ w1bf,
                         int nseg) {
    int i = blockIdx.x * 256 + threadIdx.x;
    if (i < nseg * H) num[i] = 0.0f;
    if (i < nseg) denom[i] = 0.0f;
    if (i < H * H) {
        int j = i >> 7;               // row of W1 (output feature)
        float f = W1[i];
        unsigned int u = __float_as_uint(f);
        unsigned short b = (unsigned short)((u + 0x7fffu + ((u >> 16) & 1u)) >> 16); // RNE
        // Pre-swizzle at 16B-chunk granularity: elem idx ^ ((row&7)<<3)
        int dst = i ^ ((j & 7) << 3);
        w1bf[dst] = b;
    }
}

__global__ __launch_bounds__(512) void gat_main(
    const float* __restrict__ x, const int* __restrict__ bi,
    const unsigned short* __restrict__ w1bf, const float* __restrict__ b1,
    const float* __restrict__ w2, const float* __restrict__ b2p,
    float* __restrict__ num, float* __restrict__ denom, int E) {

    __shared__ uint4 ldsW[2048];     // 32 KB: W1 bf16, pre-swizzled chunks

    const int t = threadIdx.x;
    const int lane = t & 63;
    const int w = t >> 6;            // wave 0..7, each owns 16 rows per tile
    const int lr = lane & 15;
    const int lg = lane >> 4;

    // Stage pre-swizzled W1 into LDS once (linear copy)
    const uint4* w1v = (const uint4*)w1bf;
#pragma unroll
    for (int k = 0; k < 4; ++k) ldsW[k * 512 + t] = w1v[k * 512 + t];

    float b1v[8], w2v[8];
#pragma unroll
    for (int nf = 0; nf < 8; ++nf) { b1v[nf] = b1[nf * 16 + lr]; w2v[nf] = w2[nf * 16 + lr]; }
    const float b2v = b2p[0];

    __syncthreads();                 // only barrier; main loop is barrier-free

    const int ntiles = (E + TILE - 1) / TILE;
    const int npairs = (ntiles + 1) >> 1;
    const int p0 = (int)(((long)blockIdx.x * npairs) / NB);
    const int p1 = (int)(((long)(blockIdx.x + 1) * npairs) / NB);
    if (p0 >= p1) return;

    const float4* x4 = (const float4*)x;
    const int coff = lg * 2;         // float4 offset within row for this lane

    // ---- per-wave pooling (barrier-free) ----
    auto pool = [&](bf16x8 af[4], float e, int seg, int base) {
        int sfirst = __shfl(seg, 0, 64);
        int slast  = __shfl(seg, 15, 64);
        if (sfirst == slast) {
            // value-splitting butterfly over the 16 lr-lanes (30 shuffles)
            float v[32];
#pragma unroll
            for (int ks = 0; ks < 4; ++ks)
#pragma unroll
                for (int el = 0; el < 8; ++el)
                    v[ks * 8 + el] = e * (float)af[ks][el];
            {
                const bool h0 = lr & 1;
#pragma unroll
                for (int j = 0; j < 16; ++j) {
                    float send = h0 ? v[j] : v[j + 16];
                    float recv = __shfl_xor(send, 1, 64);
                    v[j] = (h0 ? v[j + 16] : v[j]) + recv;
                }
                const bool h1 = lr & 2;
#pragma unroll
                for (int j = 0; j < 8; ++j) {
                    float send = h1 ? v[j] : v[j + 8];
                    float recv = __shfl_xor(send, 2, 64);
                    v[j] = (h1 ? v[j + 8] : v[j]) + recv;
                }
                const bool h2 = lr & 4;
#pragma unroll
                for (int j = 0; j < 4; ++j) {
                    float send = h2 ? v[j] : v[j + 4];
                    float recv = __shfl_xor(send, 4, 64);
                    v[j] = (h2 ? v[j + 4] : v[j]) + recv;
                }
                const bool h3 = lr & 8;
#pragma unroll
                for (int j = 0; j < 2; ++j) {
                    float send = h3 ? v[j] : v[j + 2];
                    float recv = __shfl_xor(send, 8, 64);
                    v[j] = (h3 ? v[j + 2] : v[j]) + recv;
                }
            }
            int i0 = ((lr & 1) << 4) | ((lr & 2) << 2) | (lr & 4) | ((lr & 8) >> 2);
            int col0 = (i0 >> 3) * 32 + lg * 8 + (i0 & 7);
            atomicAdd(&num[sfirst * H + col0], v[0]);
            atomicAdd(&num[sfirst * H + col0 + 1], v[1]);
            // denom: each e appears once per lg group -> 64-lane reduce / 4
            float d = e;
#pragma unroll
            for (int m = 1; m <= 32; m <<= 1) d += __shfl_xor(d, m, 64);
            if (lane == 0) atomicAdd(&denom[sfirst], d * 0.25f);
        } else {
            // mixed-segment wave (rare): shuffle-serialized over the 16 rows
            const int c0 = lane * 2, c1 = c0 + 1;
            float a0 = 0.f, a1 = 0.f, d = 0.f;
            int cur = sfirst;
            for (int r = 0; r < 16; ++r) {
                int sr = __shfl(seg, r, 64);
                float er = __shfl(e, r, 64);
                if (sr != cur) {
                    atomicAdd(&num[cur * H + c0], a0);
                    atomicAdd(&num[cur * H + c1], a1);
                    if (lane == 0) atomicAdd(&denom[cur], d);
                    a0 = a1 = d = 0.f; cur = sr;
                }
                int rr = base + w * 16 + r; rr = rr < E ? rr : E - 1;
                const float* xr = x + (size_t)rr * H;
                a0 = fmaf(er, xr[c0], a0);
                a1 = fmaf(er, xr[c1], a1);
                d += er;
            }
            atomicAdd(&num[cur * H + c0], a0);
            atomicAdd(&num[cur * H + c1], a1);
            if (lane == 0) atomicAdd(&denom[cur], d);
        }
    };

    auto issue_pair = [&](int pair, float4 pf[16]) {
        int ra = pair * 2 * TILE + w * 16 + lr;       ra = ra < E ? ra : E - 1;
        int rb = pair * 2 * TILE + TILE + w * 16 + lr; rb = rb < E ? rb : E - 1;
        const float4* pa = x4 + (size_t)ra * 32 + coff;
        const float4* pb = x4 + (size_t)rb * 32 + coff;
#pragma unroll
        for (int ks = 0; ks < 4; ++ks) {
            pf[ks * 2]         = pa[ks * 8];
            pf[ks * 2 + 1]     = pa[ks * 8 + 1];
            pf[8 + ks * 2]     = pb[ks * 8];
            pf[8 + ks * 2 + 1] = pb[ks * 8 + 1];
        }
    };

    float4 pf[16];
    issue_pair(p0, pf);                               // prologue prefetch

    for (int p = p0; p < p1; ++p) {
        // ---- convert in-flight pair -> bf16 A-fragments (drains vmcnt) ----
        bf16x8 afA[4], afB[4];
#pragma unroll
        for (int ks = 0; ks < 4; ++ks) {
            float4 u0 = pf[ks * 2],     u1 = pf[ks * 2 + 1];
            float4 v0 = pf[8 + ks * 2], v1 = pf[8 + ks * 2 + 1];
            bf16x8 a, b;
            a[0] = (__bf16)u0.x; a[1] = (__bf16)u0.y; a[2] = (__bf16)u0.z; a[3] = (__bf16)u0.w;
            a[4] = (__bf16)u1.x; a[5] = (__bf16)u1.y; a[6] = (__bf16)u1.z; a[7] = (__bf16)u1.w;
            b[0] = (__bf16)v0.x; b[1] = (__bf16)v0.y; b[2] = (__bf16)v0.z; b[3] = (__bf16)v0.w;
            b[4] = (__bf16)v1.x; b[5] = (__bf16)v1.y; b[6] = (__bf16)v1.z; b[7] = (__bf16)v1.w;
            afA[ks] = a; afB[ks] = b;
        }

        // ---- issue next pair's loads (in flight under all compute below) ----
        if (p + 1 < p1) issue_pair(p + 1, pf);

        // ---- MFMA: one B-frag read feeds both tiles ----
        f32x4 acca[8], accb[8];
#pragma unroll
        for (int nf = 0; nf < 8; ++nf) { acca[nf] = (f32x4)0.f; accb[nf] = (f32x4)0.f; }
#pragma unroll
        for (int ks = 0; ks < 4; ++ks) {
#pragma unroll
            for (int nf = 0; nf < 8; ++nf) {
                int j = nf * 16 + lr;
                int chunk = (j * 16 + ks * 4 + lg) ^ (j & 7);   // XOR swizzle (bank-free)
                bf16x8 bb = __builtin_bit_cast(bf16x8, ldsW[chunk]);
                acca[nf] = __builtin_amdgcn_mfma_f32_16x16x32_bf16(afA[ks], bb, acca[nf], 0, 0, 0);
                accb[nf] = __builtin_amdgcn_mfma_f32_16x16x32_bf16(afB[ks], bb, accb[nf], 0, 0, 0);
            }
        }

        // ---- scores: sc[r] for row lg*4+r; C/D layout row=lg*4+r, col=lr ----
        float sca[4], scb[4];
#pragma unroll
        for (int r = 0; r < 4; ++r) {
            float sa = 0.f, sb = 0.f;
#pragma unroll
            for (int nf = 0; nf < 8; ++nf) {
                sa = fmaf(fmaxf(acca[nf][r] + b1v[nf], 0.f), w2v[nf], sa);
                sb = fmaf(fmaxf(accb[nf][r] + b1v[nf], 0.f), w2v[nf], sb);
            }
            sca[r] = sa; scb[r] = sb;
        }
#pragma unroll
        for (int m = 1; m <= 8; m <<= 1)
#pragma unroll
            for (int r = 0; r < 4; ++r) {
                sca[r] += __shfl_xor(sca[r], m, 64);
                scb[r] += __shfl_xor(scb[r], m, 64);
            }

        // ---- e for this lane's row (row index = lr within wave's 16) ----
        const int src = ((lr >> 2) << 4) | lr;        // a lane in lg-group lr>>2
        float ea4[4], eb4[4];
#pragma unroll
        for (int r = 0; r < 4; ++r) { ea4[r] = __shfl(sca[r], src, 64); eb4[r] = __shfl(scb[r], src, 64); }
        const int rr = lr & 3;
        float sa_ = rr == 0 ? ea4[0] : rr == 1 ? ea4[1] : rr == 2 ? ea4[2] : ea4[3];
        float sb_ = rr == 0 ? eb4[0] : rr == 1 ? eb4[1] : rr == 2 ? eb4[2] : eb4[3];

        const int basea = p * 2 * TILE, baseb = basea + TILE;
        const int rowa = basea + w * 16 + lr, rowb = baseb + w * 16 + lr;
        float ea = (rowa < E) ? __expf(sa_ + b2v) : 0.f;
        float eb = (rowb < E) ? __expf(sb_ + b2v) : 0.f;

        int sega = bi[rowa < E ? rowa : E - 1];
        int segb = bi[rowb < E ? rowb : E - 1];

        pool(afA, ea, sega, basea);
        pool(afB, eb, segb, baseb);
    }
}

__global__ void gat_fin(const float* __restrict__ num, const float* __restrict__ denom,
                        float* __restrict__ out, int n) {
    int i = blockIdx.x * 256 + threadIdx.x;
    if (i < n) {
        float d = denom[i >> 7];
        out[i] = (d > 0.0f) ? num[i] / d : 0.0f;
    }
}

extern "C" void kernel_launch(void* const* d_in, const int* in_sizes, int n_in,
                              void* d_out, int out_size, void* d_ws, size_t ws_size,
                              hipStream_t stream) {
    const float* x  = (const float*)d_in[0];
    const int*   bi = (const int*)d_in[1];
    const float* W1 = (const float*)d_in[2];
    const float* b1 = (const float*)d_in[3];
    const float* w2 = (const float*)d_in[4];
    const float* b2 = (const float*)d_in[5];
    const int E = in_sizes[1];
    const int nseg = out_size / H;

    float* num = (float*)d_ws;                               // nseg*H f32
    float* denom = num + (size_t)nseg * H;                   // nseg f32
    unsigned short* w1bf = (unsigned short*)(denom + nseg);  // H*H bf16 (16B-aligned)

    int initN = nseg * H > H * H ? nseg * H : H * H;
    gat_init<<<(initN + 255) / 256, 256, 0, stream>>>(W1, num, denom, w1bf, nseg);
    gat_main<<<NB, 512, 0, stream>>>(x, bi, w1bf, b1, w2, b2, num, denom, E);
    gat_fin<<<(out_size + 255) / 256, 256, 0, stream>>>(num, denom, (float*)d_out, out_size);
}